// Round 6
// baseline (499.581 us; speedup 1.0000x reference)
//
#include <hip/hip_runtime.h>

typedef unsigned short ushort_t;
typedef __bf16 bf16x8 __attribute__((ext_vector_type(8)));
typedef float f32x4 __attribute__((ext_vector_type(4)));

__device__ __forceinline__ ushort_t f2bf(float f) {
  unsigned u = __float_as_uint(f);
  u += 0x7fff + ((u >> 16) & 1);
  return (ushort_t)(u >> 16);
}

// ---------------- weight fp32 -> bf16, pack qk bias, zero stats2 ----------------
__global__ __launch_bounds__(256) void cvt_weights(
    const float* __restrict__ wq, const float* __restrict__ wk,
    const float* __restrict__ wv, const float* __restrict__ wo,
    const float* __restrict__ bq, const float* __restrict__ bk,
    ushort_t* __restrict__ dst, float* __restrict__ qkbias,
    float* __restrict__ stats2) {
  int b = blockIdx.x, t = threadIdx.x;
  if (b < 1024) {
    int i = b * 256 + t;
    dst[i]          = f2bf(wq[i]);
    dst[262144 + i] = f2bf(wk[i]);
    dst[524288 + i] = f2bf(wv[i]);
    dst[786432 + i] = f2bf(wo[i]);
  } else if (b < 1028) {
    int j = (b - 1024) * 256 + t;  // 0..1023
    qkbias[j] = (j < 512) ? bq[j] : bk[j - 512];
  } else {
    if (t < 128) stats2[t] = 0.f;
  }
}

// ---------------- zero the rowsum accumulator ----------------
__global__ __launch_bounds__(256) void zero_f32(float* __restrict__ p) {
  p[blockIdx.x * 256 + threadIdx.x] = 0.f;
}

// ---------------- group norm partial stats: 4 blocks per (b,g) ----------------
__global__ __launch_bounds__(256) void gn_stats_partial(const float* __restrict__ x,
                                                        float* __restrict__ stats2) {
  int bg = blockIdx.x >> 2, q = blockIdx.x & 3;
  const float4* p = (const float4*)(x + (size_t)bg * 65536 + q * 16384);
  float s = 0.f, ss = 0.f;
  for (int i = threadIdx.x; i < 4096; i += 256) {
    float4 v = p[i];
    s += v.x + v.y + v.z + v.w;
    ss += v.x * v.x + v.y * v.y + v.z * v.z + v.w * v.w;
  }
  for (int off = 32; off; off >>= 1) {
    s += __shfl_xor(s, off, 64);
    ss += __shfl_xor(ss, off, 64);
  }
  __shared__ float sh[8];
  int wave = threadIdx.x >> 6, lane = threadIdx.x & 63;
  if (lane == 0) { sh[wave] = s; sh[4 + wave] = ss; }
  __syncthreads();
  if (threadIdx.x == 0) {
    atomicAdd(&stats2[bg * 2], sh[0] + sh[1] + sh[2] + sh[3]);
    atomicAdd(&stats2[bg * 2 + 1], sh[4] + sh[5] + sh[6] + sh[7]);
  }
}

__global__ __launch_bounds__(64) void gn_finalize(const float* __restrict__ stats2,
                                                  float* __restrict__ stats) {
  int t = threadIdx.x;  // 64 groups total (2 batches x 32)
  float s = stats2[t * 2], ss = stats2[t * 2 + 1];
  float mean = s * (1.f / 65536.f);
  float var = ss * (1.f / 65536.f) - mean * mean;
  stats[t * 2] = mean;
  stats[t * 2 + 1] = rsqrtf(var + 1e-6f);
}

// ---------------- GN apply + transpose: x (b,c,n) -> hnT (b,n,c) bf16 ----------------
__global__ __launch_bounds__(256) void gn_apply(
    const float* __restrict__ x, const float* __restrict__ gamma,
    const float* __restrict__ beta, const float* __restrict__ stats,
    ushort_t* __restrict__ hnT) {
  __shared__ float T[32][33];
  int i0 = blockIdx.x * 32, c0 = blockIdx.y * 32, b = blockIdx.z;
  int tx = threadIdx.x, ty = threadIdx.y;  // (32,8)
#pragma unroll
  for (int k = 0; k < 4; k++) {
    int cl = ty + k * 8;
    int c = c0 + cl;
    int bg = (b * 32 + (c >> 4)) * 2;
    float mean = stats[bg], rstd = stats[bg + 1];
    float v = x[((size_t)(b * 512 + c)) * 4096 + i0 + tx];
    T[cl][tx] = (v - mean) * rstd * gamma[c] + beta[c];
  }
  __syncthreads();
#pragma unroll
  for (int k = 0; k < 4; k++) {
    int il = ty + k * 8;
    hnT[((size_t)b * 4096 + i0 + il) * 512 + c0 + tx] = f2bf(T[tx][il]);
  }
}

// ---------------- C = A * B^T GEMM, 128 x BN tile, DIRECT-GLOBAL fragments ----
// No LDS, no barriers: each wave loads its MFMA fragments straight from global
// (per-instruction: 16 rows x 64B fully-utilized L2 lines; quads cover the
// K-window of each row). 2-stage register ping-pong gives one MFMA phase of
// load flight time; compiler emits fine-grained vmcnt. B-fragment ni at lane
// l16 = row n0+wn+l16*4+ni -> acc holds 4 consecutive out columns (packed st).
template <int BN>
__global__ __launch_bounds__(256, 3) void gemm_abt(
    const ushort_t* __restrict__ A, long long sA, int lda,
    const ushort_t* __restrict__ B, long long sB, int ldb,
    int K, int N, int ldc,
    ushort_t* __restrict__ outB, long long sC,
    const float* __restrict__ bias, int bias_mode, float scale,
    float* __restrict__ outF, const float* __restrict__ resid,
    float* __restrict__ rowsum, const float* __restrict__ colscale, int swiz) {
  constexpr int MI = (BN == 128) ? 4 : 2;
  constexpr int NI = 4;

  int bx = blockIdx.x, by = blockIdx.y, bz = blockIdx.z;
  if (swiz) {
    unsigned nx = gridDim.x, ny = gridDim.y;
    unsigned id = (blockIdx.z * ny + blockIdx.y) * nx + blockIdx.x;
    unsigned pb8 = (nx * ny) >> 3;   // per-batch blocks / 8
    unsigned c = id & 7, j = id >> 3;
    bz = j / pb8;
    unsigned jb = j - bz * pb8;
    unsigned jy = jb / nx;
    by = c * (ny >> 3) + jy;
    bx = jb - jy * nx;
  }

  int m0 = by * 128, n0 = bx * BN;
  int t = threadIdx.x;
  int lane = t & 63;
  int quad = lane >> 4, l16 = lane & 15;
  int wave = t >> 6;
  int wm = (BN == 128) ? (wave >> 1) * 64 : wave * 32;
  int wn = (BN == 128) ? (wave & 1) * 64 : 0;

  // per-lane fragment base pointers (k varies by immediate)
  const ushort_t* pA[MI];
  const ushort_t* pB[NI];
#pragma unroll
  for (int i = 0; i < MI; i++)
    pA[i] = A + (size_t)bz * sA + (size_t)(m0 + wm + i * 16 + l16) * lda + quad * 8;
#pragma unroll
  for (int j = 0; j < NI; j++)
    pB[j] = B + (size_t)bz * sB + (size_t)(n0 + wn + l16 * 4 + j) * ldb + quad * 8;

  f32x4 acc[MI][NI];
#pragma unroll
  for (int i = 0; i < MI; i++)
#pragma unroll
    for (int j = 0; j < NI; j++)
#pragma unroll
      for (int r = 0; r < 4; r++) acc[i][j][r] = 0.f;

  bf16x8 a0[MI], b0[NI], a1[MI], b1[NI];
#pragma unroll
  for (int i = 0; i < MI; i++) a0[i] = *(const bf16x8*)(pA[i]);
#pragma unroll
  for (int j = 0; j < NI; j++) b0[j] = *(const bf16x8*)(pB[j]);

  for (int k0 = 0; k0 < K; k0 += 64) {
    // stage 1 loads (k0+32) — always valid: K is a multiple of 64
#pragma unroll
    for (int i = 0; i < MI; i++) a1[i] = *(const bf16x8*)(pA[i] + k0 + 32);
#pragma unroll
    for (int j = 0; j < NI; j++) b1[j] = *(const bf16x8*)(pB[j] + k0 + 32);
#pragma unroll
    for (int mi = 0; mi < MI; mi++)
#pragma unroll
      for (int ni = 0; ni < NI; ni++)
        acc[mi][ni] = __builtin_amdgcn_mfma_f32_16x16x32_bf16(a0[mi], b0[ni], acc[mi][ni], 0, 0, 0);
    if (k0 + 64 < K) {
#pragma unroll
      for (int i = 0; i < MI; i++) a0[i] = *(const bf16x8*)(pA[i] + k0 + 64);
#pragma unroll
      for (int j = 0; j < NI; j++) b0[j] = *(const bf16x8*)(pB[j] + k0 + 64);
    }
#pragma unroll
    for (int mi = 0; mi < MI; mi++)
#pragma unroll
      for (int ni = 0; ni < NI; ni++)
        acc[mi][ni] = __builtin_amdgcn_mfma_f32_16x16x32_bf16(a1[mi], b1[ni], acc[mi][ni], 0, 0, 0);
  }

  // epilogue: lane l16, tile ni = column n0 + wn + l16*4 + ni (4 consecutive)
  size_t cbase = (size_t)bz * sC;
  int gnb = n0 + wn + l16 * 4;
  float cs4[4] = {1.f, 1.f, 1.f, 1.f};
  if (colscale) {
    float4 c4 = *(const float4*)&colscale[(size_t)bz * N + gnb];
    cs4[0] = 1.f / c4.x; cs4[1] = 1.f / c4.y; cs4[2] = 1.f / c4.z; cs4[3] = 1.f / c4.w;
  }
  float b4[4] = {0.f, 0.f, 0.f, 0.f};
  if (bias_mode == 2) {
    float4 t4 = *(const float4*)&bias[gnb];
    b4[0] = t4.x; b4[1] = t4.y; b4[2] = t4.z; b4[3] = t4.w;
  }
#pragma unroll
  for (int mi = 0; mi < MI; mi++) {
#pragma unroll
    for (int r = 0; r < 4; r++) {
      int m = m0 + wm + mi * 16 + quad * 4 + r;
      float rbias = (bias_mode == 1) ? bias[m] : 0.f;
      float v4[4];
      float rs = 0.f;
#pragma unroll
      for (int ni = 0; ni < NI; ni++) {
        float val = acc[mi][ni][r];
        if (colscale) val *= cs4[ni];
        val += (bias_mode == 2) ? b4[ni] : rbias;
        val *= scale;
        if (rowsum) { val = __expf(val); rs += val; }
        v4[ni] = val;
      }
      size_t idx = cbase + (size_t)m * ldc + gnb;
      if (outF) {
        float4 rv = *(const float4*)&resid[idx];
        float4 ov = make_float4(v4[0] + rv.x, v4[1] + rv.y, v4[2] + rv.z, v4[3] + rv.w);
        *(float4*)&outF[idx] = ov;
      } else {
        unsigned lo = (unsigned)f2bf(v4[0]) | ((unsigned)f2bf(v4[1]) << 16);
        unsigned hi = (unsigned)f2bf(v4[2]) | ((unsigned)f2bf(v4[3]) << 16);
        *(uint2*)&outB[idx] = make_uint2(lo, hi);
      }
      if (rowsum) {
        rs += __shfl_xor(rs, 1, 64);
        rs += __shfl_xor(rs, 2, 64);
        rs += __shfl_xor(rs, 4, 64);
        rs += __shfl_xor(rs, 8, 64);
        if (l16 == 0) atomicAdd(&rowsum[(size_t)bz * 4096 + m], rs);
      }
    }
  }
}

extern "C" void kernel_launch(void* const* d_in, const int* in_sizes, int n_in,
                              void* d_out, int out_size, void* d_ws, size_t ws_size,
                              hipStream_t stream) {
  const float* x     = (const float*)d_in[0];
  const float* gamma = (const float*)d_in[1];
  const float* beta  = (const float*)d_in[2];
  const float* wq    = (const float*)d_in[3];
  const float* bq    = (const float*)d_in[4];
  const float* wk    = (const float*)d_in[5];
  const float* bk    = (const float*)d_in[6];
  const float* wv    = (const float*)d_in[7];
  const float* bv    = (const float*)d_in[8];
  const float* wo    = (const float*)d_in[9];
  const float* bo    = (const float*)d_in[10];
  float* out = (float*)d_out;

  // workspace layout (bf16 elements)
  ushort_t* wb  = (ushort_t*)d_ws;     // [wq;wk] 1024x512, wv, wo
  ushort_t* wvb = wb + 524288;
  ushort_t* wob = wb + 786432;
  ushort_t* hnT = wb + 1048576;        // 2 x 4096 x 512
  ushort_t* qkT = hnT + 4194304;       // 2 x 4096 x 1024 (q cols 0-511, k cols 512-1023)
  ushort_t* vC  = qkT + 8388608;       // 2 x 512 x 4096
  ushort_t* OT  = vC + 4194304;        // 2 x 4096 x 512
  ushort_t* S   = OT + 4194304;        // 2 x 4096 x 4096 (holds P = exp(scale*S))
  float* fbuf   = (float*)(S + 33554432);
  float* stats  = fbuf;                // 128
  float* stats2 = fbuf + 128;          // 128
  float* qkbias = fbuf + 256;          // 1024
  float* l      = (float*)hnT;         // 2 x 4096 row sums (hnT dead after v-GEMM)

  const long long HS = 2097152;   // 4096*512 per batch
  const long long QS = 4194304;   // 4096*1024 per batch
  const long long SS = 16777216;  // 4096*4096 per batch
  const float scale = 0.044194173824159216f;  // 512^-0.5

  cvt_weights<<<dim3(1029), dim3(256), 0, stream>>>(wq, wk, wv, wo, bq, bk, wb, qkbias, stats2);
  gn_stats_partial<<<dim3(256), dim3(256), 0, stream>>>(x, stats2);
  gn_finalize<<<dim3(1), dim3(64), 0, stream>>>(stats2, stats);
  gn_apply<<<dim3(128, 16, 2), dim3(32, 8), 0, stream>>>(x, gamma, beta, stats, hnT);
  // qkT = hnT * [wq;wk]^T  (M=4096, N=1024, K=512), packed col bias
  gemm_abt<128><<<dim3(8, 32, 2), dim3(256), 0, stream>>>(
      hnT, HS, 512, wb, 0, 512, 512, 1024, 1024, qkT, QS, qkbias, 2, 1.f,
      nullptr, nullptr, nullptr, nullptr, 1);
  // vC = wv * hnT^T  (M=512, N=4096, K=512), row bias
  gemm_abt<64><<<dim3(64, 4, 2), dim3(256), 0, stream>>>(
      wvb, 0, 512, hnT, HS, 512, 512, 4096, 4096, vC, HS, bv, 1, 1.f,
      nullptr, nullptr, nullptr, nullptr, 0);
  // hnT dead; reuse as rowsum l
  zero_f32<<<dim3(32), dim3(256), 0, stream>>>(l);
  // P = exp(scale * q*k^T) with fused row sums (M=N=4096, K=512)
  gemm_abt<128><<<dim3(32, 32, 2), dim3(256), 0, stream>>>(
      qkT, QS, 1024, qkT + 512, QS, 1024, 512, 4096, 4096, S, SS, nullptr, 0, scale,
      nullptr, nullptr, l, nullptr, 1);
  // OT = P * vC^T (M=4096, N=512, K=4096), unnormalized; swizzled for P-row L2 share
  gemm_abt<64><<<dim3(8, 32, 2), dim3(256), 0, stream>>>(
      S, SS, 4096, vC, HS, 4096, 4096, 512, 512, OT, HS, nullptr, 0, 1.f,
      nullptr, nullptr, nullptr, nullptr, 1);
  // y = wo * (OT/l)^T + bo + x (M=512, N=4096, K=512), fp32 out + residual
  gemm_abt<64><<<dim3(64, 4, 2), dim3(256), 0, stream>>>(
      wob, 0, 512, OT, HS, 512, 512, 4096, 4096, nullptr, HS, bo, 1, 1.f,
      out, x, nullptr, l, 0);
}